// Round 3
// baseline (598.989 us; speedup 1.0000x reference)
//
#include <hip/hip_runtime.h>

#define S 2048
#define D 768
#define NH 12
#define HD 64
#define TD (3 * D)
#define GBK 64

typedef __bf16 bf16_t;
typedef __bf16 v8bf __attribute__((ext_vector_type(8)));
typedef __bf16 v4bf __attribute__((ext_vector_type(4)));
typedef float v4f __attribute__((ext_vector_type(4)));

// ---------- weight-conversion geometry (float4 units) ----------
#define NW0 (TD * D / 4)
#define NW1 (D * D / 4)
#define NW2 ((D / 2) * D / 4)
#define NW3 (D * (D / 2) / 4)
#define NWALL (NW0 + NW1 + NW2 + NW3)
#define CVTB (NWALL / 256)  // 2880, exact

// ---------- shared-memory union: max(GEMM dbuf 57344B, attn 38912B) ----------
union SMemU {
    bf16_t g[2 * (128 + 96) * GBK];  // 57344 B — QKV 128x96 double buffer
    struct {
        int idx[4][128];      // per-wave neighbor list
        float q[4][D];        // per-wave query row (f32)
        float p[4][NH * 128]; // per-wave scores/probs
    } at;
};

// ---------- manual grid barrier (device globals: zero-init, self-restoring) ----------
__device__ unsigned g_cnt = 0;
__device__ unsigned g_gen = 0;

__device__ __forceinline__ void grid_sync(int nb) {
    __syncthreads();  // drains vmcnt/lgkmcnt for whole block before t0 fences
    if (threadIdx.x == 0) {
        __threadfence();  // release: L2 writeback (agent scope)
        unsigned g = __hip_atomic_load(&g_gen, __ATOMIC_RELAXED, __HIP_MEMORY_SCOPE_AGENT);
        unsigned a = __hip_atomic_fetch_add(&g_cnt, 1u, __ATOMIC_ACQ_REL, __HIP_MEMORY_SCOPE_AGENT) + 1;
        if (a == (unsigned)nb) {
            __hip_atomic_store(&g_cnt, 0u, __ATOMIC_RELAXED, __HIP_MEMORY_SCOPE_AGENT);
            __hip_atomic_fetch_add(&g_gen, 1u, __ATOMIC_RELEASE, __HIP_MEMORY_SCOPE_AGENT);
        } else {
            while (__hip_atomic_load(&g_gen, __ATOMIC_ACQUIRE, __HIP_MEMORY_SCOPE_AGENT) == g)
                __builtin_amdgcn_s_sleep(2);
        }
        __threadfence();  // acquire: L1/L2 invalidate before next phase's reads
    }
    __syncthreads();
}

// ---------- reductions ----------
__device__ __forceinline__ float wave_reduce_sum(float v) {
#pragma unroll
    for (int o = 32; o > 0; o >>= 1) v += __shfl_down(v, o, 64);
    return v;
}
__device__ float block_reduce_sum(float v) {
    __shared__ float t4[4];
    int lane = threadIdx.x & 63, wid = threadIdx.x >> 6;
    v = wave_reduce_sum(v);
    __syncthreads();
    if (lane == 0) t4[wid] = v;
    __syncthreads();
    return t4[0] + t4[1] + t4[2] + t4[3];
}

// counted vmcnt wait with literal immediates
template <int N>
__device__ __forceinline__ void wait_vmcnt() {
    if constexpr (N == 0) asm volatile("s_waitcnt vmcnt(0)" ::: "memory");
    else if constexpr (N == 1) asm volatile("s_waitcnt vmcnt(1)" ::: "memory");
    else if constexpr (N == 2) asm volatile("s_waitcnt vmcnt(2)" ::: "memory");
    else if constexpr (N == 3) asm volatile("s_waitcnt vmcnt(3)" ::: "memory");
    else if constexpr (N == 4) asm volatile("s_waitcnt vmcnt(4)" ::: "memory");
    else if constexpr (N == 5) asm volatile("s_waitcnt vmcnt(5)" ::: "memory");
    else if constexpr (N == 6) asm volatile("s_waitcnt vmcnt(6)" ::: "memory");
    else if constexpr (N == 7) asm volatile("s_waitcnt vmcnt(7)" ::: "memory");
    else asm volatile("s_waitcnt vmcnt(8)" ::: "memory");
}

// ---------- phase helpers ----------
__device__ void addln_row(int row, int t, const float* __restrict__ A, const float* __restrict__ Bv,
                          const float* __restrict__ g, const float* __restrict__ be,
                          bf16_t* __restrict__ out) {
    const float* a = A + (size_t)row * D;
    const float* b = Bv + (size_t)row * D;
    float x[3];
    float s = 0.f;
#pragma unroll
    for (int i = 0; i < 3; ++i) { int c = t + 256 * i; x[i] = a[c] + b[c]; s += x[i]; }
    float mean = block_reduce_sum(s) * (1.0f / D);
    float vs = 0.f;
#pragma unroll
    for (int i = 0; i < 3; ++i) { float d = x[i] - mean; vs += d * d; }
    float var = block_reduce_sum(vs) * (1.0f / D);
    float rstd = rsqrtf(var + 1e-5f);
#pragma unroll
    for (int i = 0; i < 3; ++i) {
        int c = t + 256 * i;
        out[(size_t)row * D + c] = (bf16_t)((x[i] - mean) * rstd * g[c] + be[c]);
    }
}

template <typename TO>
__device__ void ln_row(int row, int t, const bf16_t* __restrict__ X,
                       const float* __restrict__ g, const float* __restrict__ be, TO* __restrict__ out) {
    const bf16_t* a = X + (size_t)row * D;
    float x[3];
    float s = 0.f;
#pragma unroll
    for (int i = 0; i < 3; ++i) { int c = t + 256 * i; x[i] = (float)a[c]; s += x[i]; }
    float mean = block_reduce_sum(s) * (1.0f / D);
    float vs = 0.f;
#pragma unroll
    for (int i = 0; i < 3; ++i) { float d = x[i] - mean; vs += d * d; }
    float var = block_reduce_sum(vs) * (1.0f / D);
    float rstd = rsqrtf(var + 1e-5f);
#pragma unroll
    for (int i = 0; i < 3; ++i) {
        int c = t + 256 * i;
        out[(size_t)row * D + c] = (TO)((x[i] - mean) * rstd * g[c] + be[c]);
    }
}

__device__ void cvt_chunk(int ci, int t,
                          const float* __restrict__ s0, const float* __restrict__ s1,
                          const float* __restrict__ s2, const float* __restrict__ s3,
                          bf16_t* __restrict__ d0, bf16_t* __restrict__ d1,
                          bf16_t* __restrict__ d2, bf16_t* __restrict__ d3) {
    int i = ci * 256 + t;
    const float* sp; bf16_t* dp;
    if (i < NW0) { sp = s0; dp = d0; }
    else if (i < NW0 + NW1) { sp = s1; dp = d1; i -= NW0; }
    else if (i < NW0 + NW1 + NW2) { sp = s2; dp = d2; i -= NW0 + NW1; }
    else if (i < NWALL) { sp = s3; dp = d3; i -= NW0 + NW1 + NW2; }
    else return;
    float4 v = ((const float4*)sp)[i];
    v4bf o = {(bf16_t)v.x, (bf16_t)v.y, (bf16_t)v.z, (bf16_t)v.w};
    *(v4bf*)(dp + (size_t)i * 4) = o;
}

// ---------- MFMA GEMM tile (proven dbuf + counted-vmcnt structure) ----------
template <int TM, int TN, int RELU, bool RESID>
__device__ void gemm_tile(bf16_t* __restrict__ smem, int bx, int by,
                          const bf16_t* __restrict__ A, const bf16_t* __restrict__ B,
                          const float* __restrict__ bias, const bf16_t* __restrict__ Rsd,
                          bf16_t* __restrict__ C, int M, int N, int K) {
    constexpr int CA = TM * 8;
    constexpr int CHUNKS = (TM + TN) * 8;
    constexpr int P = CHUNKS / 256;
    static_assert(CHUNKS % 256 == 0, "chunk passes must be exact");
    constexpr int MI = TM / 32, NI = TN / 32;
    constexpr int BUFE = (TM + TN) * GBK;
    const int t = threadIdx.x;
    const int lane = t & 63, wave = t >> 6;
    const int wr = (wave >> 1) * (TM / 2), wc = (wave & 1) * (TN / 2);
    const int m0 = by * TM, n0 = bx * TN;
    const int lm = lane & 15, q = lane >> 4;

    const bf16_t* gp[P];
    int loff[P];
#pragma unroll
    for (int p = 0; p < P; ++p) {
        int c = t + 256 * p;
        if (c < CA) {
            int slab = c / (TM * 4), r4 = c % (TM * 4);
            gp[p] = A + (size_t)(m0 + (r4 >> 2)) * K + slab * 32 + (r4 & 3) * 8;
            loff[p] = slab * (TM * 32) + r4 * 8;
        } else {
            int cc = c - CA;
            int slab = cc / (TN * 4), r4 = cc % (TN * 4);
            gp[p] = B + (size_t)(n0 + (r4 >> 2)) * K + slab * 32 + (r4 & 3) * 8;
            loff[p] = TM * GBK + slab * (TN * 32) + r4 * 8;
        }
    }

    v4f acc[MI][NI] = {};

    auto stage = [&](int buf, int k0) {
#pragma unroll
        for (int p = 0; p < P; ++p)
            __builtin_amdgcn_global_load_lds(
                (const __attribute__((address_space(1))) void*)(gp[p] + k0),
                (__attribute__((address_space(3))) void*)(smem + buf * BUFE + loff[p]), 16, 0, 0);
    };

    stage(0, 0);
    int cur = 0;
    for (int k0 = 0; k0 < K; k0 += GBK) {
        if (k0 + GBK < K) {
            stage(cur ^ 1, k0 + GBK);
            __builtin_amdgcn_sched_barrier(0);
            wait_vmcnt<P>();
        } else {
            __builtin_amdgcn_sched_barrier(0);
            wait_vmcnt<0>();
        }
        __builtin_amdgcn_s_barrier();
        __builtin_amdgcn_sched_barrier(0);

        const bf16_t* As = smem + cur * BUFE;
        const bf16_t* Bs = As + TM * GBK;
        v8bf af[2][MI], bfr[2][NI];
#pragma unroll
        for (int s = 0; s < 2; ++s) {
#pragma unroll
            for (int i = 0; i < MI; ++i)
                af[s][i] = *(const v8bf*)(As + s * (TM * 32) + (wr + i * 16 + lm) * 32 + q * 8);
#pragma unroll
            for (int j = 0; j < NI; ++j)
                bfr[s][j] = *(const v8bf*)(Bs + s * (TN * 32) + (wc + j * 16 + lm) * 32 + q * 8);
        }
#pragma unroll
        for (int s = 0; s < 2; ++s)
#pragma unroll
            for (int i = 0; i < MI; ++i)
#pragma unroll
                for (int j = 0; j < NI; ++j)
                    acc[i][j] = __builtin_amdgcn_mfma_f32_16x16x32_bf16(af[s][i], bfr[s][j], acc[i][j], 0, 0, 0);
        __builtin_amdgcn_sched_barrier(0);
        __builtin_amdgcn_s_barrier();
        cur ^= 1;
    }

    // D mapping (verified m89/m91): row = quad*4 + reg, col = lane&15
#pragma unroll
    for (int i = 0; i < MI; ++i)
#pragma unroll
        for (int j = 0; j < NI; ++j) {
            int col = n0 + wc + j * 16 + lm;
            float bs = bias[col];
#pragma unroll
            for (int r = 0; r < 4; ++r) {
                int row = m0 + wr + i * 16 + q * 4 + r;
                float v = acc[i][j][r] + bs;
                if (RELU) v = fmaxf(v, 0.f);
                if (RESID) v += (float)Rsd[(size_t)row * N + col];
                C[(size_t)row * N + col] = (bf16_t)v;
            }
        }
}

// ---------- attention: one wave per query row (ballot compaction, no atomics) ----------
__device__ void attn_row(int row, int lane, const bf16_t* __restrict__ qkv, const int* __restrict__ adj,
                         bf16_t* __restrict__ O, int* __restrict__ widx,
                         float* __restrict__ wq, float* __restrict__ wp) {
    int cnt = 0;
    const int4* arow = (const int4*)(adj + (size_t)row * S);
    const unsigned long long lt = (1ull << lane) - 1;
#pragma unroll
    for (int p = 0; p < 8; ++p) {
        int4 v = arow[lane + 64 * p];
        int base = (lane + 64 * p) * 4;
        int f[4] = {v.x, v.y, v.z, v.w};
#pragma unroll
        for (int c = 0; c < 4; ++c) {
            unsigned long long m = __ballot(f[c] != 0);
            if (f[c]) {
                int k = cnt + (int)__popcll(m & lt);
                if (k < 128) widx[k] = base + c;
            }
            cnt += (int)__popcll(m);
        }
    }
    const int n = (cnt < 128) ? cnt : 128;

    for (int ch = lane; ch < D / 8; ch += 64) {
        v8bf qv = *(const v8bf*)(qkv + (size_t)row * TD + ch * 8);
#pragma unroll
        for (int e = 0; e < 8; ++e) wq[ch * 8 + e] = (float)qv[e];
    }
    __syncthreads();

    for (int it = lane; it < n * NH; it += 64) {
        int h = it / n, i = it - h * n;
        const bf16_t* kp = qkv + (size_t)widx[i] * TD + D + h * HD;
        const float* qp = wq + h * HD;
        float dot = 0.f;
#pragma unroll
        for (int c = 0; c < HD; c += 8) {
            v8bf kv = *(const v8bf*)(kp + c);
#pragma unroll
            for (int e = 0; e < 8; ++e) dot += qp[c + e] * (float)kv[e];
        }
        wp[h * 128 + i] = dot * 0.125f;  // 1/sqrt(64)
    }
    __syncthreads();

    for (int h = 0; h < NH; ++h) {
        float v0 = (lane < n) ? wp[h * 128 + lane] : -1e30f;
        float v1 = (lane + 64 < n) ? wp[h * 128 + lane + 64] : -1e30f;
        float m = fmaxf(v0, v1);
#pragma unroll
        for (int o = 32; o > 0; o >>= 1) m = fmaxf(m, __shfl_xor(m, o, 64));
        float p0 = (lane < n) ? __expf(v0 - m) : 0.f;
        float p1 = (lane + 64 < n) ? __expf(v1 - m) : 0.f;
        float sm = p0 + p1;
#pragma unroll
        for (int o = 32; o > 0; o >>= 1) sm += __shfl_xor(sm, o, 64);
        float inv = 1.f / sm;
        if (lane < n) wp[h * 128 + lane] = p0 * inv;
        if (lane + 64 < n) wp[h * 128 + lane + 64] = p1 * inv;
    }
    __syncthreads();

    float acc[NH] = {};
    for (int i = 0; i < n; ++i) {
        const bf16_t* vp = qkv + (size_t)widx[i] * TD + 2 * D + lane;
#pragma unroll
        for (int j = 0; j < NH; ++j) acc[j] += wp[j * 128 + i] * (float)vp[j * HD];
    }
#pragma unroll
    for (int j = 0; j < NH; ++j) O[(size_t)row * D + j * HD + lane] = (bf16_t)acc[j];
}

// ---------- the fused kernel (regular launch + manual grid barrier) ----------
struct KArgs {
    const float *exp_e, *pert, *w_in, *b_in, *w_out, *b_out;
    const float *g0, *be0, *g1, *be1, *g2, *be2;
    const float *w1, *b1, *w2, *b2;
    const int* adj;
    float* out;
    bf16_t *wb_in, *wb_out, *wb_1, *wb_2;
    bf16_t *x_in, *qkv, *attn_o, *y1, *x1, *ffh, *y2;
};

__global__ __launch_bounds__(256, 2) void mega(KArgs a, int nb) {
    __shared__ SMemU sm;
    const int blk = blockIdx.x, t = threadIdx.x;
    const int lane = t & 63, wave = t >> 6;

    // P0: add+LN (units < S) + weight conversion (units S..S+CVTB)
    for (int u = blk; u < S + CVTB; u += nb) {
        if (u < S) addln_row(u, t, a.exp_e, a.pert, a.g0, a.be0, a.x_in);
        else cvt_chunk(u - S, t, a.w_in, a.w_out, a.w1, a.w2, a.wb_in, a.wb_out, a.wb_1, a.wb_2);
    }
    grid_sync(nb);

    // P1: QKV GEMM, tiles 128x96 -> 24x16 = 384
    for (int tile = blk; tile < 384; tile += nb)
        gemm_tile<128, 96, 0, false>(sm.g, tile % 24, tile / 24, a.x_in, a.wb_in, a.b_in, nullptr, a.qkv, S, TD, D);
    grid_sync(nb);

    // P2: sparse attention, one wave per row; stride nb*4 ∈ {1024,2048} divides S
    for (int row = blk * 4 + wave; row < S; row += nb * 4)
        attn_row(row, lane, a.qkv, a.adj, a.attn_o, sm.at.idx[wave], sm.at.q[wave], sm.at.p[wave]);
    grid_sync(nb);

    // P3: out-proj + residual(x_in), tiles 64x64 -> 12x32 = 384
    for (int tile = blk; tile < 384; tile += nb)
        gemm_tile<64, 64, 0, true>(sm.g, tile % 12, tile / 12, a.attn_o, a.wb_out, a.b_out, a.x_in, a.y1, S, D, D);
    grid_sync(nb);

    // P4: ln1
    for (int u = blk; u < S; u += nb) ln_row<bf16_t>(u, t, a.y1, a.g1, a.be1, a.x1);
    grid_sync(nb);

    // P5: FF1 + ReLU, tiles 32x64 -> 6x64 = 384
    for (int tile = blk; tile < 384; tile += nb)
        gemm_tile<32, 64, 1, false>(sm.g, tile % 6, tile / 6, a.x1, a.wb_1, a.b1, nullptr, a.ffh, S, D / 2, D);
    grid_sync(nb);

    // P6: FF2 + residual(x1), tiles 64x64 -> 12x32 = 384 (K=384)
    for (int tile = blk; tile < 384; tile += nb)
        gemm_tile<64, 64, 0, true>(sm.g, tile % 12, tile / 12, a.ffh, a.wb_2, a.b2, a.x1, a.y2, S, D, D / 2);
    grid_sync(nb);

    // P7: ln2 -> f32 output
    for (int u = blk; u < S; u += nb) ln_row<float>(u, t, a.y2, a.g2, a.be2, a.out);
}

// ---------- launch ----------
extern "C" void kernel_launch(void* const* d_in, const int* in_sizes, int n_in,
                              void* d_out, int out_size, void* d_ws, size_t ws_size,
                              hipStream_t stream) {
    const size_t SD = (size_t)S * D;
    bf16_t* wb_in  = (bf16_t*)d_ws;
    bf16_t* wb_out = wb_in + (size_t)TD * D;
    bf16_t* wb_1   = wb_out + (size_t)D * D;
    bf16_t* wb_2   = wb_1 + (size_t)(D / 2) * D;
    bf16_t* x_in   = wb_2 + (size_t)D * (D / 2);
    bf16_t* qkv    = x_in + SD;
    bf16_t* attn_o = qkv + 3 * SD;
    bf16_t* y1     = attn_o + SD;
    bf16_t* x1     = y1 + SD;
    bf16_t* ffh    = x1 + SD;
    bf16_t* y2     = ffh + SD / 2;

    KArgs a;
    a.exp_e = (const float*)d_in[0];
    a.pert  = (const float*)d_in[1];
    a.w_in  = (const float*)d_in[2];
    a.b_in  = (const float*)d_in[3];
    a.w_out = (const float*)d_in[4];
    a.b_out = (const float*)d_in[5];
    a.g0  = (const float*)d_in[6];
    a.be0 = (const float*)d_in[7];
    a.g1  = (const float*)d_in[8];
    a.be1 = (const float*)d_in[9];
    a.g2  = (const float*)d_in[10];
    a.be2 = (const float*)d_in[11];
    a.w1  = (const float*)d_in[12];
    a.b1  = (const float*)d_in[13];
    a.w2  = (const float*)d_in[14];
    a.b2  = (const float*)d_in[15];
    a.adj = (const int*)d_in[16];
    a.out = (float*)d_out;
    a.wb_in = wb_in; a.wb_out = wb_out; a.wb_1 = wb_1; a.wb_2 = wb_2;
    a.x_in = x_in; a.qkv = qkv; a.attn_o = attn_o; a.y1 = y1; a.x1 = x1; a.ffh = ffh; a.y2 = y2;

    // Deadlock-proof grid: 512 only if >=2 blocks/CU is certain; else 256
    // (>=1 block/CU always holds: 57.4KB LDS < 160KB, VGPR<=256 via launch_bounds).
    static int nb_cache = 0;
    if (nb_cache == 0) {
        int occ = 0;
        hipError_t e = hipOccupancyMaxActiveBlocksPerMultiprocessor(&occ, mega, 256, 0);
        nb_cache = (e == hipSuccess && occ >= 2) ? 512 : 256;
    }
    mega<<<nb_cache, 256, 0, stream>>>(a, nb_cache);
}

// Round 4
// 191.223 us; speedup vs baseline: 3.1324x; 3.1324x over previous
//
#include <hip/hip_runtime.h>

#define S 2048
#define D 768
#define NH 12
#define HD 64
#define TD (3 * D)
#define GBK 64

typedef __bf16 bf16_t;
typedef __bf16 v8bf __attribute__((ext_vector_type(8)));
typedef __bf16 v4bf __attribute__((ext_vector_type(4)));
typedef float v4f __attribute__((ext_vector_type(4)));

// ---------- reductions ----------
__device__ __forceinline__ float wave_reduce_sum(float v) {
#pragma unroll
    for (int o = 32; o > 0; o >>= 1) v += __shfl_down(v, o, 64);
    return v;
}
__device__ __forceinline__ float wave_allreduce_sum(float v) {
#pragma unroll
    for (int o = 32; o > 0; o >>= 1) v += __shfl_xor(v, o, 64);
    return v;
}
__device__ float block_reduce_sum(float v) {
    __shared__ float t4[4];
    int lane = threadIdx.x & 63, wid = threadIdx.x >> 6;
    v = wave_reduce_sum(v);
    __syncthreads();
    if (lane == 0) t4[wid] = v;
    __syncthreads();
    return t4[0] + t4[1] + t4[2] + t4[3];
}

// counted vmcnt wait with literal immediates
template <int N>
__device__ __forceinline__ void wait_vmcnt() {
    if constexpr (N == 0) asm volatile("s_waitcnt vmcnt(0)" ::: "memory");
    else if constexpr (N == 1) asm volatile("s_waitcnt vmcnt(1)" ::: "memory");
    else if constexpr (N == 2) asm volatile("s_waitcnt vmcnt(2)" ::: "memory");
    else if constexpr (N == 3) asm volatile("s_waitcnt vmcnt(3)" ::: "memory");
    else if constexpr (N == 4) asm volatile("s_waitcnt vmcnt(4)" ::: "memory");
    else if constexpr (N == 5) asm volatile("s_waitcnt vmcnt(5)" ::: "memory");
    else if constexpr (N == 6) asm volatile("s_waitcnt vmcnt(6)" ::: "memory");
    else if constexpr (N == 7) asm volatile("s_waitcnt vmcnt(7)" ::: "memory");
    else asm volatile("s_waitcnt vmcnt(8)" ::: "memory");
}

// ---------- fused: blocks [0,S) do add+LN; blocks [S, S+2880) convert weights ----------
#define NW0 (TD * D / 4)
#define NW1 (D * D / 4)
#define NW2 ((D / 2) * D / 4)
#define NW3 (D * (D / 2) / 4)
#define NWALL (NW0 + NW1 + NW2 + NW3)

__global__ __launch_bounds__(256) void addln_cvt(const float* __restrict__ A, const float* __restrict__ Bv,
                                                 const float* __restrict__ g, const float* __restrict__ be,
                                                 bf16_t* __restrict__ out,
                                                 const float* __restrict__ s0, const float* __restrict__ s1,
                                                 const float* __restrict__ s2, const float* __restrict__ s3,
                                                 bf16_t* __restrict__ d0, bf16_t* __restrict__ d1,
                                                 bf16_t* __restrict__ d2, bf16_t* __restrict__ d3) {
    int blk = blockIdx.x, t = threadIdx.x;
    if (blk >= S) {
        int i = (blk - S) * 256 + t;
        const float* sp; bf16_t* dp;
        if (i < NW0) { sp = s0; dp = d0; }
        else if (i < NW0 + NW1) { sp = s1; dp = d1; i -= NW0; }
        else if (i < NW0 + NW1 + NW2) { sp = s2; dp = d2; i -= NW0 + NW1; }
        else if (i < NWALL) { sp = s3; dp = d3; i -= NW0 + NW1 + NW2; }
        else return;
        float4 v = ((const float4*)sp)[i];
        v4bf o = {(bf16_t)v.x, (bf16_t)v.y, (bf16_t)v.z, (bf16_t)v.w};
        *(v4bf*)(dp + (size_t)i * 4) = o;
        return;
    }
    int row = blk;
    const float* a = A + (size_t)row * D;
    const float* b = Bv + (size_t)row * D;
    float x[3];
    float s = 0.f;
#pragma unroll
    for (int i = 0; i < 3; ++i) { int c = t + 256 * i; x[i] = a[c] + b[c]; s += x[i]; }
    float mean = block_reduce_sum(s) * (1.0f / D);
    float vs = 0.f;
#pragma unroll
    for (int i = 0; i < 3; ++i) { float d = x[i] - mean; vs += d * d; }
    float var = block_reduce_sum(vs) * (1.0f / D);
    float rstd = rsqrtf(var + 1e-5f);
#pragma unroll
    for (int i = 0; i < 3; ++i) {
        int c = t + 256 * i;
        out[(size_t)row * D + c] = (bf16_t)((x[i] - mean) * rstd * g[c] + be[c]);
    }
}

// ---------- single-input LayerNorm (used for final ln2 -> f32 out) ----------
template <typename TO>
__global__ __launch_bounds__(256) void ln_only(const bf16_t* __restrict__ X,
                                               const float* __restrict__ g, const float* __restrict__ be,
                                               TO* __restrict__ out) {
    int row = blockIdx.x, t = threadIdx.x;
    const bf16_t* a = X + (size_t)row * D;
    float x[3];
    float s = 0.f;
#pragma unroll
    for (int i = 0; i < 3; ++i) { int c = t + 256 * i; x[i] = (float)a[c]; s += x[i]; }
    float mean = block_reduce_sum(s) * (1.0f / D);
    float vs = 0.f;
#pragma unroll
    for (int i = 0; i < 3; ++i) { float d = x[i] - mean; vs += d * d; }
    float var = block_reduce_sum(vs) * (1.0f / D);
    float rstd = rsqrtf(var + 1e-5f);
#pragma unroll
    for (int i = 0; i < 3; ++i) {
        int c = t + 256 * i;
        out[(size_t)row * D + c] = (TO)((x[i] - mean) * rstd * g[c] + be[c]);
    }
}

// ---------- MFMA GEMM: C[M,N] = act(A[M,K] @ B[N,K]^T + bias[N]) [+ Rsd] ----------
// BK=64 as two 32-slabs (slab-major LDS), double-buffered with counted vmcnt.
template <int TM, int TN, int RELU, bool RESID>
__global__ __launch_bounds__(256) void gemm_mfma(const bf16_t* __restrict__ A, const bf16_t* __restrict__ B,
                                                 const float* __restrict__ bias,
                                                 const bf16_t* __restrict__ Rsd, bf16_t* __restrict__ C,
                                                 int M, int N, int K) {
    constexpr int CA = TM * 8;
    constexpr int CHUNKS = (TM + TN) * 8;
    constexpr int P = CHUNKS / 256;
    static_assert(CHUNKS % 256 == 0, "chunk passes must be exact");
    constexpr int MI = TM / 32, NI = TN / 32;
    constexpr int BUFE = (TM + TN) * GBK;
    __shared__ bf16_t smem[2 * BUFE];
    const int t = threadIdx.x;
    const int lane = t & 63, wave = t >> 6;
    const int wr = (wave >> 1) * (TM / 2), wc = (wave & 1) * (TN / 2);
    const int m0 = blockIdx.y * TM, n0 = blockIdx.x * TN;
    const int lm = lane & 15, q = lane >> 4;

    const bf16_t* gp[P];
    int loff[P];
#pragma unroll
    for (int p = 0; p < P; ++p) {
        int c = t + 256 * p;
        if (c < CA) {
            int slab = c / (TM * 4), r4 = c % (TM * 4);
            gp[p] = A + (size_t)(m0 + (r4 >> 2)) * K + slab * 32 + (r4 & 3) * 8;
            loff[p] = slab * (TM * 32) + r4 * 8;
        } else {
            int cc = c - CA;
            int slab = cc / (TN * 4), r4 = cc % (TN * 4);
            gp[p] = B + (size_t)(n0 + (r4 >> 2)) * K + slab * 32 + (r4 & 3) * 8;
            loff[p] = TM * GBK + slab * (TN * 32) + r4 * 8;
        }
    }

    v4f acc[MI][NI] = {};

    auto stage = [&](int buf, int k0) {
#pragma unroll
        for (int p = 0; p < P; ++p)
            __builtin_amdgcn_global_load_lds(
                (const __attribute__((address_space(1))) void*)(gp[p] + k0),
                (__attribute__((address_space(3))) void*)(smem + buf * BUFE + loff[p]), 16, 0, 0);
    };

    stage(0, 0);
    int cur = 0;
    for (int k0 = 0; k0 < K; k0 += GBK) {
        if (k0 + GBK < K) {
            stage(cur ^ 1, k0 + GBK);
            __builtin_amdgcn_sched_barrier(0);
            wait_vmcnt<P>();
        } else {
            __builtin_amdgcn_sched_barrier(0);
            wait_vmcnt<0>();
        }
        __builtin_amdgcn_s_barrier();
        __builtin_amdgcn_sched_barrier(0);

        const bf16_t* As = smem + cur * BUFE;
        const bf16_t* Bs = As + TM * GBK;
        v8bf af[2][MI], bfr[2][NI];
#pragma unroll
        for (int s = 0; s < 2; ++s) {
#pragma unroll
            for (int i = 0; i < MI; ++i)
                af[s][i] = *(const v8bf*)(As + s * (TM * 32) + (wr + i * 16 + lm) * 32 + q * 8);
#pragma unroll
            for (int j = 0; j < NI; ++j)
                bfr[s][j] = *(const v8bf*)(Bs + s * (TN * 32) + (wc + j * 16 + lm) * 32 + q * 8);
        }
#pragma unroll
        for (int s = 0; s < 2; ++s)
#pragma unroll
            for (int i = 0; i < MI; ++i)
#pragma unroll
                for (int j = 0; j < NI; ++j)
                    acc[i][j] = __builtin_amdgcn_mfma_f32_16x16x32_bf16(af[s][i], bfr[s][j], acc[i][j], 0, 0, 0);
        __builtin_amdgcn_sched_barrier(0);
        __builtin_amdgcn_s_barrier();
        cur ^= 1;
    }

    // D mapping (verified m89/m91): row = quad*4 + reg, col = lane&15
#pragma unroll
    for (int i = 0; i < MI; ++i)
#pragma unroll
        for (int j = 0; j < NI; ++j) {
            int col = n0 + wc + j * 16 + lm;
            float bs = bias[col];
#pragma unroll
            for (int r = 0; r < 4; ++r) {
                int row = m0 + wr + i * 16 + q * 4 + r;
                float v = acc[i][j][r] + bs;
                if (RELU) v = fmaxf(v, 0.f);
                if (RESID) v += (float)Rsd[(size_t)row * N + col];
                C[(size_t)row * N + col] = (bf16_t)v;
            }
        }
}

// ---------- fused LN1 + FF1: x1 = LN(y1); ffh = relu(x1 @ w1^T + b1) ----------
// Each block covers TM=32 rows x TN=64 cols; A-tile spans full K=768 rows, so
// LN is computed block-locally (wave-per-row shuffle allreduce) straight into
// the slab-major A-LDS layout the MFMA reader expects. bx==0 writes x1 to
// global for ff2's residual. B (w1) uses the proven dbuf+counted-vmcnt loop.
#define FTM 32
#define FTN 64
__global__ __launch_bounds__(256) void ff1_fused(const bf16_t* __restrict__ Y1,
                                                 const float* __restrict__ g, const float* __restrict__ be,
                                                 const bf16_t* __restrict__ W1, const float* __restrict__ b1,
                                                 bf16_t* __restrict__ X1, bf16_t* __restrict__ FFH) {
    constexpr int K = D;             // 768
    constexpr int NSLAB = K / 32;    // 24
    constexpr int NOUT = D / 2;      // 384
    constexpr int CB = FTN * 8;      // 512 B-chunks per 64-K step
    constexpr int P = CB / 256;      // 2
    constexpr int NI = FTN / 32;     // 2
    __shared__ bf16_t Afull[NSLAB * FTM * 32];  // 49152 B (all K resident)
    __shared__ bf16_t Bs[2 * FTN * GBK];        // 16384 B dbuf
    const int t = threadIdx.x;
    const int lane = t & 63, wave = t >> 6;
    const int m0 = blockIdx.y * FTM, n0 = blockIdx.x * FTN;
    const int lm = lane & 15, q = lane >> 4;

    // ---- LN: wave w handles rows w*8..w*8+7; lane owns chunks {lane, lane+64<96} ----
    float ga0[8], bb0[8], ga1[8], bb1[8];
#pragma unroll
    for (int e = 0; e < 8; ++e) { ga0[e] = g[lane * 8 + e]; bb0[e] = be[lane * 8 + e]; }
    if (lane < 32) {
#pragma unroll
        for (int e = 0; e < 8; ++e) { ga1[e] = g[(lane + 64) * 8 + e]; bb1[e] = be[(lane + 64) * 8 + e]; }
    }
    for (int rr = 0; rr < 8; ++rr) {
        const int r = wave * 8 + rr, gr = m0 + r;
        float xa[8], xb[8];
        float s = 0.f;
        v8bf ya = *(const v8bf*)(Y1 + (size_t)gr * D + lane * 8);
#pragma unroll
        for (int e = 0; e < 8; ++e) { xa[e] = (float)ya[e]; s += xa[e]; }
        if (lane < 32) {
            v8bf yb = *(const v8bf*)(Y1 + (size_t)gr * D + (lane + 64) * 8);
#pragma unroll
            for (int e = 0; e < 8; ++e) { xb[e] = (float)yb[e]; s += xb[e]; }
        }
        float mean = wave_allreduce_sum(s) * (1.0f / D);
        float vs = 0.f;
#pragma unroll
        for (int e = 0; e < 8; ++e) { float d2 = xa[e] - mean; vs += d2 * d2; }
        if (lane < 32) {
#pragma unroll
            for (int e = 0; e < 8; ++e) { float d2 = xb[e] - mean; vs += d2 * d2; }
        }
        float rstd = rsqrtf(wave_allreduce_sum(vs) * (1.0f / D) + 1e-5f);
        v8bf oa;
#pragma unroll
        for (int e = 0; e < 8; ++e) oa[e] = (bf16_t)((xa[e] - mean) * rstd * ga0[e] + bb0[e]);
        // chunk ch covers cols [ch*8, ch*8+8): slab = ch>>2, col-in-slab = (ch&3)*8
        *(v8bf*)(Afull + (lane >> 2) * (FTM * 32) + r * 32 + (lane & 3) * 8) = oa;
        if (blockIdx.x == 0) *(v8bf*)(X1 + (size_t)gr * D + lane * 8) = oa;
        if (lane < 32) {
            v8bf ob;
#pragma unroll
            for (int e = 0; e < 8; ++e) ob[e] = (bf16_t)((xb[e] - mean) * rstd * ga1[e] + bb1[e]);
            const int ch = lane + 64;
            *(v8bf*)(Afull + (ch >> 2) * (FTM * 32) + r * 32 + (ch & 3) * 8) = ob;
            if (blockIdx.x == 0) *(v8bf*)(X1 + (size_t)gr * D + ch * 8) = ob;
        }
    }

    // ---- B staging setup ----
    const bf16_t* gp[P];
    int loff[P];
#pragma unroll
    for (int p = 0; p < P; ++p) {
        int c = t + 256 * p;
        int slab = c / (FTN * 4), r4 = c % (FTN * 4);
        gp[p] = W1 + (size_t)(n0 + (r4 >> 2)) * K + slab * 32 + (r4 & 3) * 8;
        loff[p] = slab * (FTN * 32) + r4 * 8;
    }
    auto stageB = [&](int buf, int k0) {
#pragma unroll
        for (int p = 0; p < P; ++p)
            __builtin_amdgcn_global_load_lds(
                (const __attribute__((address_space(1))) void*)(gp[p] + k0),
                (__attribute__((address_space(3))) void*)(Bs + buf * (FTN * GBK) + loff[p]), 16, 0, 0);
    };
    stageB(0, 0);
    // LN LDS writes visible to all waves; raw barrier (do NOT drain vmcnt prefetch)
    asm volatile("s_waitcnt lgkmcnt(0)" ::: "memory");
    __builtin_amdgcn_s_barrier();

    const int wr = (wave >> 1) * (FTM / 2);  // 0 or 16
    const int wc = (wave & 1) * (FTN / 2);   // 0 or 32
    v4f acc[NI] = {};
    int cur = 0;
    for (int k0 = 0; k0 < K; k0 += GBK) {
        if (k0 + GBK < K) {
            stageB(cur ^ 1, k0 + GBK);
            __builtin_amdgcn_sched_barrier(0);
            wait_vmcnt<P>();
        } else {
            __builtin_amdgcn_sched_barrier(0);
            wait_vmcnt<0>();
        }
        __builtin_amdgcn_s_barrier();
        __builtin_amdgcn_sched_barrier(0);

        const bf16_t* BsC = Bs + cur * (FTN * GBK);
        v8bf af[2], bfr[2][NI];
#pragma unroll
        for (int s = 0; s < 2; ++s) {
            int slab = (k0 >> 5) + s;
            af[s] = *(const v8bf*)(Afull + slab * (FTM * 32) + (wr + lm) * 32 + q * 8);
#pragma unroll
            for (int j = 0; j < NI; ++j)
                bfr[s][j] = *(const v8bf*)(BsC + s * (FTN * 32) + (wc + j * 16 + lm) * 32 + q * 8);
        }
#pragma unroll
        for (int s = 0; s < 2; ++s)
#pragma unroll
            for (int j = 0; j < NI; ++j)
                acc[j] = __builtin_amdgcn_mfma_f32_16x16x32_bf16(af[s], bfr[s][j], acc[j], 0, 0, 0);
        __builtin_amdgcn_sched_barrier(0);
        __builtin_amdgcn_s_barrier();
        cur ^= 1;
    }

#pragma unroll
    for (int j = 0; j < NI; ++j) {
        int col = n0 + wc + j * 16 + lm;
        float bs = b1[col];
#pragma unroll
        for (int r = 0; r < 4; ++r) {
            int row = m0 + wr + q * 4 + r;
            float v = acc[j][r] + bs;
            v = fmaxf(v, 0.f);
            FFH[(size_t)row * NOUT + col] = (bf16_t)v;
        }
    }
}

// ---------- attention: one wave per query row (ballot compaction; verified R3) ----------
__device__ void attn_row(int row, int lane, const bf16_t* __restrict__ qkv, const int* __restrict__ adj,
                         bf16_t* __restrict__ O, int* __restrict__ widx,
                         float* __restrict__ wq, float* __restrict__ wp) {
    int cnt = 0;
    const int4* arow = (const int4*)(adj + (size_t)row * S);
    const unsigned long long lt = (1ull << lane) - 1;
#pragma unroll
    for (int p = 0; p < 8; ++p) {
        int4 v = arow[lane + 64 * p];
        int base = (lane + 64 * p) * 4;
        int f[4] = {v.x, v.y, v.z, v.w};
#pragma unroll
        for (int c = 0; c < 4; ++c) {
            unsigned long long m = __ballot(f[c] != 0);
            if (f[c]) {
                int k = cnt + (int)__popcll(m & lt);
                if (k < 128) widx[k] = base + c;
            }
            cnt += (int)__popcll(m);
        }
    }
    const int n = (cnt < 128) ? cnt : 128;

    for (int ch = lane; ch < D / 8; ch += 64) {
        v8bf qv = *(const v8bf*)(qkv + (size_t)row * TD + ch * 8);
#pragma unroll
        for (int e = 0; e < 8; ++e) wq[ch * 8 + e] = (float)qv[e];
    }
    __syncthreads();

    for (int it = lane; it < n * NH; it += 64) {
        int h = it / n, i = it - h * n;
        const bf16_t* kp = qkv + (size_t)widx[i] * TD + D + h * HD;
        const float* qp = wq + h * HD;
        float dot = 0.f;
#pragma unroll
        for (int c = 0; c < HD; c += 8) {
            v8bf kv = *(const v8bf*)(kp + c);
#pragma unroll
            for (int e = 0; e < 8; ++e) dot += qp[c + e] * (float)kv[e];
        }
        wp[h * 128 + i] = dot * 0.125f;  // 1/sqrt(64)
    }
    __syncthreads();

    for (int h = 0; h < NH; ++h) {
        float v0 = (lane < n) ? wp[h * 128 + lane] : -1e30f;
        float v1 = (lane + 64 < n) ? wp[h * 128 + lane + 64] : -1e30f;
        float m = fmaxf(v0, v1);
#pragma unroll
        for (int o = 32; o > 0; o >>= 1) m = fmaxf(m, __shfl_xor(m, o, 64));
        float p0 = (lane < n) ? __expf(v0 - m) : 0.f;
        float p1 = (lane + 64 < n) ? __expf(v1 - m) : 0.f;
        float sm = p0 + p1;
#pragma unroll
        for (int o = 32; o > 0; o >>= 1) sm += __shfl_xor(sm, o, 64);
        float inv = 1.f / sm;
        if (lane < n) wp[h * 128 + lane] = p0 * inv;
        if (lane + 64 < n) wp[h * 128 + lane + 64] = p1 * inv;
    }
    __syncthreads();

    float acc[NH] = {};
    for (int i = 0; i < n; ++i) {
        const bf16_t* vp = qkv + (size_t)widx[i] * TD + 2 * D + lane;
#pragma unroll
        for (int j = 0; j < NH; ++j) acc[j] += wp[j * 128 + i] * (float)vp[j * HD];
    }
#pragma unroll
    for (int j = 0; j < NH; ++j) O[(size_t)row * D + j * HD + lane] = (bf16_t)acc[j];
}

__global__ __launch_bounds__(256) void attn_sparse_w(const bf16_t* __restrict__ qkv,
                                                     const int* __restrict__ adj,
                                                     bf16_t* __restrict__ O) {
    __shared__ int s_idx[4][128];
    __shared__ float s_q[4][D];
    __shared__ float s_p[4][NH * 128];
    const int lane = threadIdx.x & 63, wave = threadIdx.x >> 6;
    const int row = blockIdx.x * 4 + wave;
    attn_row(row, lane, qkv, adj, O, s_idx[wave], s_q[wave], s_p[wave]);
}

// ---------- launch ----------
extern "C" void kernel_launch(void* const* d_in, const int* in_sizes, int n_in,
                              void* d_out, int out_size, void* d_ws, size_t ws_size,
                              hipStream_t stream) {
    const float* exp_e = (const float*)d_in[0];
    const float* pert  = (const float*)d_in[1];
    const float* w_in  = (const float*)d_in[2];
    const float* b_in  = (const float*)d_in[3];
    const float* w_out = (const float*)d_in[4];
    const float* b_out = (const float*)d_in[5];
    const float* g0  = (const float*)d_in[6];
    const float* be0 = (const float*)d_in[7];
    const float* g1  = (const float*)d_in[8];
    const float* be1 = (const float*)d_in[9];
    const float* g2  = (const float*)d_in[10];
    const float* be2 = (const float*)d_in[11];
    const float* w1  = (const float*)d_in[12];
    const float* b1  = (const float*)d_in[13];
    const float* w2  = (const float*)d_in[14];
    const float* b2  = (const float*)d_in[15];
    const int*   adj = (const int*)d_in[16];
    float* out = (float*)d_out;

    const size_t SD = (size_t)S * D;
    bf16_t* wb_in  = (bf16_t*)d_ws;               // [2304*768]
    bf16_t* wb_out = wb_in + (size_t)TD * D;      // [768*768]
    bf16_t* wb_1   = wb_out + (size_t)D * D;      // [384*768]
    bf16_t* wb_2   = wb_1 + (size_t)(D / 2) * D;  // [768*384]
    bf16_t* x_in   = wb_2 + (size_t)D * (D / 2);  // [S*D]
    bf16_t* qkv    = x_in + SD;                   // [S*3D]
    bf16_t* attn_o = qkv + 3 * SD;                // [S*D]
    bf16_t* y1     = attn_o + SD;                 // [S*D] pre-LN1
    bf16_t* x1     = y1 + SD;                     // [S*D] ln1 out (for ff2 residual)
    bf16_t* ffh    = x1 + SD;                     // [S*D/2]
    bf16_t* y2     = ffh + SD / 2;                // [S*D] pre-LN2

    const int CVTB = (NWALL + 255) / 256;
    addln_cvt<<<S + CVTB, 256, 0, stream>>>(exp_e, pert, g0, be0, x_in,
                                            w_in, w_out, w1, w2, wb_in, wb_out, wb_1, wb_2);
    gemm_mfma<64, 128, 0, false><<<dim3(TD / 128, S / 64), 256, 0, stream>>>(x_in, wb_in, b_in, nullptr, qkv, S, TD, D);
    attn_sparse_w<<<S / 4, 256, 0, stream>>>(qkv, adj, attn_o);
    gemm_mfma<64, 64, 0, true><<<dim3(D / 64, S / 64), 256, 0, stream>>>(attn_o, wb_out, b_out, x_in, y1, S, D, D);
    ff1_fused<<<dim3((D / 2) / FTN, S / FTM), 256, 0, stream>>>(y1, g1, be1, wb_1, b1, x1, ffh);
    gemm_mfma<64, 64, 0, true><<<dim3(D / 64, S / 64), 256, 0, stream>>>(ffh, wb_2, b2, x1, y2, S, D, D / 2);
    ln_only<float><<<S, 256, 0, stream>>>(y2, g2, be2, out);
}